// Round 3
// baseline (250.302 us; speedup 1.0000x reference)
//
#include <hip/hip_runtime.h>
#include <hip/hip_bf16.h>

// GraphSAGE 2-layer + linear head, N=100000, d=h=128, E=640000.
// R12: keep gather+GEMM fusion (R11) but shrink M-tile 128 -> 32 to fix the
//      measured occupancy ceiling (27%: grid 782 blocks = 12 waves/CU was the
//      binding limit; gather is latency-bound random 256B rows). Now 3125
//      blocks, acc 64->16 regs, LDS 34.8->8.7 KB -> ~28 waves/CU resident.
//      Wt re-read per block (64KB x 3125 = 200MB) is L2-served (~6us agg).
//      prep unchanged (atomic floor).

#define ND 128          // feature dim
#define KTOT 256        // concat K ([agg | self])
#define CAP 32          // neighbor bucket capacity (max deg ~23 @ Poisson 6.4)
#define TM 32           // rows per block
#define AGS 136         // Agg LDS row stride in shorts (272B rows, 16B-aligned)

typedef __bf16 bf16x8 __attribute__((ext_vector_type(8)));
typedef float floatx16 __attribute__((ext_vector_type(16)));

__device__ inline unsigned short f2bf(float f) {
    union { float f; unsigned u; } v; v.f = f;
    unsigned r = v.u + 0x7fffu + ((v.u >> 16) & 1u);   // RTNE
    return (unsigned short)(r >> 16);
}
__device__ inline float bf_lo(unsigned u) { return __uint_as_float(u << 16); }
__device__ inline float bf_hi(unsigned u) { return __uint_as_float(u & 0xffff0000u); }

__device__ inline bf16x8 ldg_bf8(const unsigned short* p, bool ok) {
    int4 v = {0, 0, 0, 0};
    if (ok) v = *(const int4*)p;
    union { int4 i; bf16x8 b; } u; u.i = v;
    return u.b;
}

// ---------------- prep: interleaved jobs — 128 edges/block + convert + weights ----------------
__global__ void k_prep_all(const float* __restrict__ x, unsigned short* __restrict__ xbf,
                           int nElems,
                           const float* __restrict__ W1l, const float* __restrict__ W1r,
                           unsigned short* __restrict__ Wt1,
                           const float* __restrict__ W2l, const float* __restrict__ W2r,
                           unsigned short* __restrict__ Wt2,
                           const int* __restrict__ esrc_in, const int* __restrict__ edst_in,
                           int* __restrict__ cnt, int* __restrict__ ebuk, int E) {
    const int t = threadIdx.x;
    const int tid = blockIdx.x * 256 + t;

    // --- edge job: threads 0..127 take one edge each (coalesced 512B) ---
    const int e = blockIdx.x * 128 + t;
    const bool doE = (t < 128) && (e < E);
    int d0 = 0, s0 = 0;
    if (doE) {
        d0 = edst_in[e];
        s0 = esrc_in[e];
    }

    // --- x loads (independent; overlap the atomic below) ---
    const int i = tid * 8;
    float4 xa, xc;
    const bool doX = (i < nElems);
    if (doX) {
        xa = *(const float4*)(x + i);
        xc = *(const float4*)(x + i + 4);
    }

    // --- atomic slot claim ---
    int p0 = -1;
    if (doE) p0 = atomicAdd(&cnt[d0], 1);

    // --- convert + store (VALU/BW work hides the atomic round trip) ---
    if (doX) {
        uint4 r;
        r.x = (unsigned)f2bf(xa.x) | ((unsigned)f2bf(xa.y) << 16);
        r.y = (unsigned)f2bf(xa.z) | ((unsigned)f2bf(xa.w) << 16);
        r.z = (unsigned)f2bf(xc.x) | ((unsigned)f2bf(xc.y) << 16);
        r.w = (unsigned)f2bf(xc.z) | ((unsigned)f2bf(xc.w) << 16);
        *(uint4*)(xbf + i) = r;
    }

    // --- weight transpose+convert (tiny) ---
    if (tid < 2 * KTOT * ND) {
        const int half = tid >> 15;            // 0 -> layer1, 1 -> layer2
        const int idx = tid & 32767;
        const int nn = idx >> 8;               // output col
        const int kk = idx & 255;              // concat K
        const float* Wl = half ? W2l : W1l;
        const float* Wr = half ? W2r : W1r;
        unsigned short* Wt = half ? Wt2 : Wt1;
        float v = (kk < 128) ? Wl[(size_t)kk * ND + nn] : Wr[(size_t)(kk - 128) * ND + nn];
        Wt[(size_t)nn * KTOT + kk] = f2bf(v);
    }

    // --- dependent scatter store ---
    if (p0 >= 0 && p0 < CAP) ebuk[d0 * CAP + p0] = s0;
}

// ---------------- fused gather: TM rows -> Agg LDS (16 lanes/node, TM/16 passes) ----------------
__device__ __forceinline__ void gatherTM(const unsigned short* __restrict__ feat,
                                         const int* __restrict__ cnt,
                                         const int* __restrict__ ebuk,
                                         int n, int m0, int t,
                                         unsigned short* Agg) {
    const int l = t & 15;
    const int g = t >> 4;
#pragma unroll
    for (int p = 0; p < TM / 16; ++p) {
        const int nl = p * 16 + g;             // node_local 0..TM-1
        const int node = m0 + nl;
        int d = 0;
        if (node < n) d = cnt[node];
        const int dd = min(d, CAP);
        const int* lst = ebuk + (size_t)node * CAP;
        float a0 = 0, a1 = 0, a2 = 0, a3 = 0, a4 = 0, a5 = 0, a6 = 0, a7 = 0;
        const int capi = dd - 1;               // valid when dd>0 (loop guarded by j<dd)
        for (int j = 0; j < dd; j += 4) {
            int s0 = lst[j];
            int s1 = lst[min(j + 1, capi)];
            int s2 = lst[min(j + 2, capi)];
            int s3 = lst[min(j + 3, capi)];
            uint4 v0 = ((const uint4*)(feat + (size_t)s0 * ND))[l];
            uint4 v1 = ((const uint4*)(feat + (size_t)s1 * ND))[l];
            uint4 v2 = ((const uint4*)(feat + (size_t)s2 * ND))[l];
            uint4 v3 = ((const uint4*)(feat + (size_t)s3 * ND))[l];
            if (j + 1 >= dd) { v1.x = v1.y = v1.z = v1.w = 0u; }
            if (j + 2 >= dd) { v2.x = v2.y = v2.z = v2.w = 0u; }
            if (j + 3 >= dd) { v3.x = v3.y = v3.z = v3.w = 0u; }
            a0 += bf_lo(v0.x) + bf_lo(v1.x) + bf_lo(v2.x) + bf_lo(v3.x);
            a1 += bf_hi(v0.x) + bf_hi(v1.x) + bf_hi(v2.x) + bf_hi(v3.x);
            a2 += bf_lo(v0.y) + bf_lo(v1.y) + bf_lo(v2.y) + bf_lo(v3.y);
            a3 += bf_hi(v0.y) + bf_hi(v1.y) + bf_hi(v2.y) + bf_hi(v3.y);
            a4 += bf_lo(v0.z) + bf_lo(v1.z) + bf_lo(v2.z) + bf_lo(v3.z);
            a5 += bf_hi(v0.z) + bf_hi(v1.z) + bf_hi(v2.z) + bf_hi(v3.z);
            a6 += bf_lo(v0.w) + bf_lo(v1.w) + bf_lo(v2.w) + bf_lo(v3.w);
            a7 += bf_hi(v0.w) + bf_hi(v1.w) + bf_hi(v2.w) + bf_hi(v3.w);
        }
        float inv = 1.0f / (float)max(d, 1);
        uint4 r;
        r.x = (unsigned)f2bf(a0 * inv) | ((unsigned)f2bf(a1 * inv) << 16);
        r.y = (unsigned)f2bf(a2 * inv) | ((unsigned)f2bf(a3 * inv) << 16);
        r.z = (unsigned)f2bf(a4 * inv) | ((unsigned)f2bf(a5 * inv) << 16);
        r.w = (unsigned)f2bf(a6 * inv) | ((unsigned)f2bf(a7 * inv) << 16);
        *(uint4*)&Agg[nl * AGS + l * 8] = r;
    }
}

// ---------------- fused layer 1: gather + MFMA GEMM (32-row tile, 4 N-waves) ----------------
__launch_bounds__(256, 4)
__global__ void k_layer1_fused(const unsigned short* __restrict__ feat,
                               const unsigned short* __restrict__ Wt,
                               const float* __restrict__ bias,
                               const int* __restrict__ cnt,
                               const int* __restrict__ ebuk,
                               unsigned short* __restrict__ out, int n) {
    __shared__ __align__(16) unsigned short Agg[TM * AGS];
    const int t = threadIdx.x;
    const int m0 = blockIdx.x * TM;

    gatherTM(feat, cnt, ebuk, n, m0, t, Agg);
    __syncthreads();

    const int wave = t >> 6, lane = t & 63;
    const int l31 = lane & 31, lhalf = lane >> 5;
    const int wn = wave * 32;                  // 4 waves split N=128 into 32-col slabs

    floatx16 acc = (floatx16)0.0f;

    // K half 1: A from Agg LDS (rows 0..31 shared by all waves)
#pragma unroll
    for (int kc = 0; kc < 4; ++kc) {
        const int k0 = kc * 32;
        bf16x8 af[2], bfr[2];
#pragma unroll
        for (int ks = 0; ks < 2; ++ks) {
            af[ks]  = *(const bf16x8*)&Agg[l31 * AGS + k0 + ks * 16 + lhalf * 8];
            bfr[ks] = *(const bf16x8*)(Wt + (size_t)(wn + l31) * KTOT + k0 + ks * 16 + lhalf * 8);
        }
        acc = __builtin_amdgcn_mfma_f32_32x32x16_bf16(af[0], bfr[0], acc, 0, 0, 0);
        acc = __builtin_amdgcn_mfma_f32_32x32x16_bf16(af[1], bfr[1], acc, 0, 0, 0);
    }

    // K half 2: A (self rows) direct from global — L1/L2-served
    const int rA0 = m0 + l31;
    const bool okA = rA0 < n;
#pragma unroll
    for (int kc = 4; kc < 8; ++kc) {
        const int k0 = kc * 32;        // B col base (128..224)
        const int ka = k0 - 128;       // self col base
        bf16x8 af[2], bfr[2];
#pragma unroll
        for (int ks = 0; ks < 2; ++ks) {
            af[ks]  = ldg_bf8(feat + (size_t)rA0 * ND + ka + ks * 16 + lhalf * 8, okA);
            bfr[ks] = *(const bf16x8*)(Wt + (size_t)(wn + l31) * KTOT + k0 + ks * 16 + lhalf * 8);
        }
        acc = __builtin_amdgcn_mfma_f32_32x32x16_bf16(af[0], bfr[0], acc, 0, 0, 0);
        acc = __builtin_amdgcn_mfma_f32_32x32x16_bf16(af[1], bfr[1], acc, 0, 0, 0);
    }

    // epilogue: relu + bf16 store. C/D: col=lane&31, row=(reg&3)+8*(reg>>2)+4*(lane>>5)
    const int c = wn + l31;
    const float bv = bias[c];
#pragma unroll
    for (int reg = 0; reg < 16; ++reg) {
        const int row = m0 + lhalf * 4 + (reg & 3) + 8 * (reg >> 2);
        if (row < n) {
            float v = fmaxf(acc[reg] + bv, 0.f);
            out[(size_t)row * ND + c] = f2bf(v);
        }
    }
}

// ---------------- fused layer 2 + linear head (32-row tile) ----------------
__launch_bounds__(256, 4)
__global__ void k_layer2_fused_head(const unsigned short* __restrict__ feat,
                                    const unsigned short* __restrict__ Wt,
                                    const float* __restrict__ bias,
                                    const float* __restrict__ Wlin,
                                    const float* __restrict__ blin,
                                    const int* __restrict__ cnt,
                                    const int* __restrict__ ebuk,
                                    float* __restrict__ out, int n) {
    __shared__ __align__(16) unsigned short Agg[TM * AGS];
    __shared__ float part[TM][4];
    const int t = threadIdx.x;
    const int m0 = blockIdx.x * TM;

    gatherTM(feat, cnt, ebuk, n, m0, t, Agg);
    __syncthreads();

    const int wave = t >> 6, lane = t & 63;
    const int l31 = lane & 31, lhalf = lane >> 5;
    const int wn = wave * 32;

    floatx16 acc = (floatx16)0.0f;

#pragma unroll
    for (int kc = 0; kc < 4; ++kc) {
        const int k0 = kc * 32;
        bf16x8 af[2], bfr[2];
#pragma unroll
        for (int ks = 0; ks < 2; ++ks) {
            af[ks]  = *(const bf16x8*)&Agg[l31 * AGS + k0 + ks * 16 + lhalf * 8];
            bfr[ks] = *(const bf16x8*)(Wt + (size_t)(wn + l31) * KTOT + k0 + ks * 16 + lhalf * 8);
        }
        acc = __builtin_amdgcn_mfma_f32_32x32x16_bf16(af[0], bfr[0], acc, 0, 0, 0);
        acc = __builtin_amdgcn_mfma_f32_32x32x16_bf16(af[1], bfr[1], acc, 0, 0, 0);
    }

    const int rA0 = m0 + l31;
    const bool okA = rA0 < n;
#pragma unroll
    for (int kc = 4; kc < 8; ++kc) {
        const int k0 = kc * 32;
        const int ka = k0 - 128;
        bf16x8 af[2], bfr[2];
#pragma unroll
        for (int ks = 0; ks < 2; ++ks) {
            af[ks]  = ldg_bf8(feat + (size_t)rA0 * ND + ka + ks * 16 + lhalf * 8, okA);
            bfr[ks] = *(const bf16x8*)(Wt + (size_t)(wn + l31) * KTOT + k0 + ks * 16 + lhalf * 8);
        }
        acc = __builtin_amdgcn_mfma_f32_32x32x16_bf16(af[0], bfr[0], acc, 0, 0, 0);
        acc = __builtin_amdgcn_mfma_f32_32x32x16_bf16(af[1], bfr[1], acc, 0, 0, 0);
    }

    // fused epilogue: p[reg] = sum_c relu(h2[row][c]) * Wlin[c] over this wave's 32 cols,
    // reduced across the 32 lanes; 4 waves' partials combined via LDS.
    const int c = wn + l31;
    const float bv = bias[c];
    const float wv = Wlin[c];
    float p[16];
#pragma unroll
    for (int reg = 0; reg < 16; ++reg)
        p[reg] = fmaxf(acc[reg] + bv, 0.f) * wv;
#pragma unroll
    for (int reg = 0; reg < 16; ++reg) {
        float v = p[reg];
        v += __shfl_xor(v, 1);
        v += __shfl_xor(v, 2);
        v += __shfl_xor(v, 4);
        v += __shfl_xor(v, 8);
        v += __shfl_xor(v, 16);
        if (l31 == 0) {
            int rl = lhalf * 4 + (reg & 3) + 8 * (reg >> 2);
            part[rl][wave] = v;
        }
    }
    __syncthreads();
    if (t < TM) {
        int row = m0 + t;
        if (row < n)
            out[row] = part[t][0] + part[t][1] + part[t][2] + part[t][3] + blin[0];
    }
}

extern "C" void kernel_launch(void* const* d_in, const int* in_sizes, int n_in,
                              void* d_out, int out_size, void* d_ws, size_t ws_size,
                              hipStream_t stream) {
    const float* x    = (const float*)d_in[0];
    const int*   edge = (const int*)d_in[1];    // [2, E]
    const float* W1l  = (const float*)d_in[2];
    const float* b1   = (const float*)d_in[3];
    const float* W1r  = (const float*)d_in[4];
    const float* W2l  = (const float*)d_in[5];
    const float* b2   = (const float*)d_in[6];
    const float* W2r  = (const float*)d_in[7];
    const float* Wlin = (const float*)d_in[8];
    const float* blin = (const float*)d_in[9];
    float* out = (float*)d_out;

    int n = out_size;               // 100000 nodes
    int E = in_sizes[1] / 2;        // 640000 edges
    (void)n_in; (void)ws_size;

    char* ws = (char*)d_ws;
    size_t off = 0;
    auto take = [&](size_t bytes) -> char* {
        char* p = ws + off;
        off += (bytes + 255) & ~(size_t)255;
        return p;
    };
    int* cnt    = (int*)take((size_t)n * 4);
    int* ebuk   = (int*)take((size_t)n * CAP * 4);
    unsigned short* xbf  = (unsigned short*)take((size_t)n * ND * 2);
    unsigned short* h1bf = (unsigned short*)take((size_t)n * ND * 2);
    unsigned short* Wt1  = (unsigned short*)take((size_t)ND * KTOT * 2);
    unsigned short* Wt2  = (unsigned short*)take((size_t)ND * KTOT * 2);

    hipMemsetAsync(cnt, 0, (size_t)n * 4, stream);

    const int* esrc_in = edge;       // row 0: src
    const int* edst_in = edge + E;   // row 1: dst

    int nElems = n * ND;                         // 12.8M
    int prepBlocks = (nElems / 8 + 255) / 256;   // 6250; 128 edges/block covers E=640k

    k_prep_all<<<prepBlocks, 256, 0, stream>>>(
        x, xbf, nElems, W1l, W1r, Wt1, W2l, W2r, Wt2,
        esrc_in, edst_in, cnt, ebuk, E);

    int gemmBlocks = (n + TM - 1) / TM;          // 3125

    // layer 1 (gather + GEMM fused)
    k_layer1_fused<<<gemmBlocks, 256, 0, stream>>>(xbf, Wt1, b1, cnt, ebuk, h1bf, n);
    // layer 2 + head (gather + GEMM + head fused; h2 never materialized)
    k_layer2_fused_head<<<gemmBlocks, 256, 0, stream>>>(h1bf, Wt2, b2, Wlin, blin, cnt, ebuk, out, n);
}

// Round 4
// 215.371 us; speedup vs baseline: 1.1622x; 1.1622x over previous
//
#include <hip/hip_runtime.h>
#include <hip/hip_bf16.h>

// GraphSAGE 2-layer + linear head, N=100000, d=h=128, E=640000.
// R13: R12 fused structure, but eliminate scattered global MFMA fragment loads
//      (each was 32 cache lines per wave instr — the real 66us cost, not
//      occupancy). Wt is packed in prep into exact fragment order (1KB fully
//      coalesced wave loads, L2-resident). Self rows staged coalesced into LDS
//      and fragments read from LDS (same 0-conflict pattern as Agg).
//      LDS 17.4KB/block -> 8 blocks/CU. prep unchanged except Wt pack index.

#define ND 128          // feature dim
#define KTOT 256        // concat K ([agg | self])
#define CAP 32          // neighbor bucket capacity (max deg ~23 @ Poisson 6.4)
#define TM 32           // rows per block
#define AGS 136         // LDS row stride in shorts (272B rows, 16B-aligned)

typedef __bf16 bf16x8 __attribute__((ext_vector_type(8)));
typedef float floatx16 __attribute__((ext_vector_type(16)));

__device__ inline unsigned short f2bf(float f) {
    union { float f; unsigned u; } v; v.f = f;
    unsigned r = v.u + 0x7fffu + ((v.u >> 16) & 1u);   // RTNE
    return (unsigned short)(r >> 16);
}
__device__ inline float bf_lo(unsigned u) { return __uint_as_float(u << 16); }
__device__ inline float bf_hi(unsigned u) { return __uint_as_float(u & 0xffff0000u); }

// ---------------- prep: interleaved jobs — 128 edges/block + convert + weights ----------------
// Wt packed layout (per layer, 64KB): for output-slab n32 (0..3), kc (0..7),
// ks (0..1): a 1KB chunk of 64 lanes x 16B, lane = (lhalf<<5)|l31 holding
// W[kc*32+ks*16+lhalf*8 + 0..7][n32*32+l31]. One coalesced wave load per frag.
__global__ void k_prep_all(const float* __restrict__ x, unsigned short* __restrict__ xbf,
                           int nElems,
                           const float* __restrict__ W1l, const float* __restrict__ W1r,
                           unsigned short* __restrict__ Wt1,
                           const float* __restrict__ W2l, const float* __restrict__ W2r,
                           unsigned short* __restrict__ Wt2,
                           const int* __restrict__ esrc_in, const int* __restrict__ edst_in,
                           int* __restrict__ cnt, int* __restrict__ ebuk, int E) {
    const int t = threadIdx.x;
    const int tid = blockIdx.x * 256 + t;

    // --- edge job: threads 0..127 take one edge each (coalesced 512B) ---
    const int e = blockIdx.x * 128 + t;
    const bool doE = (t < 128) && (e < E);
    int d0 = 0, s0 = 0;
    if (doE) {
        d0 = edst_in[e];
        s0 = esrc_in[e];
    }

    // --- x loads (independent; overlap the atomic below) ---
    const int i = tid * 8;
    float4 xa, xc;
    const bool doX = (i < nElems);
    if (doX) {
        xa = *(const float4*)(x + i);
        xc = *(const float4*)(x + i + 4);
    }

    // --- atomic slot claim ---
    int p0 = -1;
    if (doE) p0 = atomicAdd(&cnt[d0], 1);

    // --- convert + store (VALU/BW work hides the atomic round trip) ---
    if (doX) {
        uint4 r;
        r.x = (unsigned)f2bf(xa.x) | ((unsigned)f2bf(xa.y) << 16);
        r.y = (unsigned)f2bf(xa.z) | ((unsigned)f2bf(xa.w) << 16);
        r.z = (unsigned)f2bf(xc.x) | ((unsigned)f2bf(xc.y) << 16);
        r.w = (unsigned)f2bf(xc.z) | ((unsigned)f2bf(xc.w) << 16);
        *(uint4*)(xbf + i) = r;
    }

    // --- weight transpose+convert into packed fragment order (tiny) ---
    if (tid < 2 * KTOT * ND) {
        const int half = tid >> 15;            // 0 -> layer1, 1 -> layer2
        const int idx = tid & 32767;
        const int nn = idx >> 8;               // output col 0..127
        const int kk = idx & 255;              // concat K 0..255
        const float* Wl = half ? W2l : W1l;
        const float* Wr = half ? W2r : W1r;
        unsigned short* Wt = half ? Wt2 : Wt1;
        float v = (kk < 128) ? Wl[(size_t)kk * ND + nn] : Wr[(size_t)(kk - 128) * ND + nn];
        const int n32 = nn >> 5, r = nn & 31;
        const int kc = kk >> 5, ks = (kk >> 4) & 1, lh = (kk >> 3) & 1, k8 = kk & 7;
        Wt[n32 * 8192 + kc * 1024 + ks * 512 + (lh * 32 + r) * 8 + k8] = f2bf(v);
    }

    // --- dependent scatter store ---
    if (p0 >= 0 && p0 < CAP) ebuk[d0 * CAP + p0] = s0;
}

// ---------------- fused gather: TM rows -> Agg LDS (16 lanes/node, TM/16 passes) ----------------
__device__ __forceinline__ void gatherTM(const unsigned short* __restrict__ feat,
                                         const int* __restrict__ cnt,
                                         const int* __restrict__ ebuk,
                                         int n, int m0, int t,
                                         unsigned short* Agg) {
    const int l = t & 15;
    const int g = t >> 4;
#pragma unroll
    for (int p = 0; p < TM / 16; ++p) {
        const int nl = p * 16 + g;             // node_local 0..TM-1
        const int node = m0 + nl;
        int d = 0;
        if (node < n) d = cnt[node];
        const int dd = min(d, CAP);
        const int* lst = ebuk + (size_t)node * CAP;
        float a0 = 0, a1 = 0, a2 = 0, a3 = 0, a4 = 0, a5 = 0, a6 = 0, a7 = 0;
        const int capi = dd - 1;               // valid when dd>0 (loop guarded by j<dd)
        for (int j = 0; j < dd; j += 4) {
            int s0 = lst[j];
            int s1 = lst[min(j + 1, capi)];
            int s2 = lst[min(j + 2, capi)];
            int s3 = lst[min(j + 3, capi)];
            uint4 v0 = ((const uint4*)(feat + (size_t)s0 * ND))[l];
            uint4 v1 = ((const uint4*)(feat + (size_t)s1 * ND))[l];
            uint4 v2 = ((const uint4*)(feat + (size_t)s2 * ND))[l];
            uint4 v3 = ((const uint4*)(feat + (size_t)s3 * ND))[l];
            if (j + 1 >= dd) { v1.x = v1.y = v1.z = v1.w = 0u; }
            if (j + 2 >= dd) { v2.x = v2.y = v2.z = v2.w = 0u; }
            if (j + 3 >= dd) { v3.x = v3.y = v3.z = v3.w = 0u; }
            a0 += bf_lo(v0.x) + bf_lo(v1.x) + bf_lo(v2.x) + bf_lo(v3.x);
            a1 += bf_hi(v0.x) + bf_hi(v1.x) + bf_hi(v2.x) + bf_hi(v3.x);
            a2 += bf_lo(v0.y) + bf_lo(v1.y) + bf_lo(v2.y) + bf_lo(v3.y);
            a3 += bf_hi(v0.y) + bf_hi(v1.y) + bf_hi(v2.y) + bf_hi(v3.y);
            a4 += bf_lo(v0.z) + bf_lo(v1.z) + bf_lo(v2.z) + bf_lo(v3.z);
            a5 += bf_hi(v0.z) + bf_hi(v1.z) + bf_hi(v2.z) + bf_hi(v3.z);
            a6 += bf_lo(v0.w) + bf_lo(v1.w) + bf_lo(v2.w) + bf_lo(v3.w);
            a7 += bf_hi(v0.w) + bf_hi(v1.w) + bf_hi(v2.w) + bf_hi(v3.w);
        }
        float inv = 1.0f / (float)max(d, 1);
        uint4 r;
        r.x = (unsigned)f2bf(a0 * inv) | ((unsigned)f2bf(a1 * inv) << 16);
        r.y = (unsigned)f2bf(a2 * inv) | ((unsigned)f2bf(a3 * inv) << 16);
        r.z = (unsigned)f2bf(a4 * inv) | ((unsigned)f2bf(a5 * inv) << 16);
        r.w = (unsigned)f2bf(a6 * inv) | ((unsigned)f2bf(a7 * inv) << 16);
        *(uint4*)&Agg[nl * AGS + l * 8] = r;
    }
}

// ---------------- stage self rows m0..m0+TM-1 into LDS (coalesced) ----------------
__device__ __forceinline__ void stageSelf(const unsigned short* __restrict__ feat,
                                          int n, int m0, int t,
                                          unsigned short* Sf) {
#pragma unroll
    for (int q = 0; q < (TM * ND / 8) / 256; ++q) {     // 512 int4 chunks / 256 threads
        const int idx = t + q * 256;                    // 0..511
        const int row = idx >> 4;                       // 16 int4 per 128-short row
        const int c16 = idx & 15;
        int4 w = {0, 0, 0, 0};
        const int gr = m0 + row;
        if (gr < n) w = *(const int4*)(feat + (size_t)gr * ND + c16 * 8);
        *(int4*)&Sf[row * AGS + c16 * 8] = w;
    }
}

// ---------------- fused layer 1: gather + MFMA GEMM (32-row tile, 4 N-waves) ----------------
__launch_bounds__(256, 8)
__global__ void k_layer1_fused(const unsigned short* __restrict__ feat,
                               const unsigned short* __restrict__ Wt,
                               const float* __restrict__ bias,
                               const int* __restrict__ cnt,
                               const int* __restrict__ ebuk,
                               unsigned short* __restrict__ out, int n) {
    __shared__ __align__(16) unsigned short Agg[TM * AGS];
    __shared__ __align__(16) unsigned short Sf[TM * AGS];
    const int t = threadIdx.x;
    const int m0 = blockIdx.x * TM;

    gatherTM(feat, cnt, ebuk, n, m0, t, Agg);
    stageSelf(feat, n, m0, t, Sf);
    __syncthreads();

    const int wave = t >> 6, lane = t & 63;
    const int l31 = lane & 31, lhalf = lane >> 5;
    const int wn = wave * 32;                  // 4 waves split N=128 into 32-col slabs
    const unsigned short* Bw = Wt + wave * 8192;

    floatx16 acc = (floatx16)0.0f;

#pragma unroll
    for (int kc = 0; kc < 8; ++kc) {
        const unsigned short* Ab = (kc < 4)
            ? &Agg[l31 * AGS + kc * 32]
            : &Sf[l31 * AGS + (kc - 4) * 32];
        bf16x8 af[2], bfr[2];
#pragma unroll
        for (int ks = 0; ks < 2; ++ks) {
            af[ks]  = *(const bf16x8*)(Ab + ks * 16 + lhalf * 8);
            bfr[ks] = *(const bf16x8*)(Bw + kc * 1024 + ks * 512 + lane * 8);
        }
        acc = __builtin_amdgcn_mfma_f32_32x32x16_bf16(af[0], bfr[0], acc, 0, 0, 0);
        acc = __builtin_amdgcn_mfma_f32_32x32x16_bf16(af[1], bfr[1], acc, 0, 0, 0);
    }

    // epilogue: relu + bf16 store. C/D: col=lane&31, row=(reg&3)+8*(reg>>2)+4*(lane>>5)
    const int c = wn + l31;
    const float bv = bias[c];
#pragma unroll
    for (int reg = 0; reg < 16; ++reg) {
        const int row = m0 + lhalf * 4 + (reg & 3) + 8 * (reg >> 2);
        if (row < n) {
            float v = fmaxf(acc[reg] + bv, 0.f);
            out[(size_t)row * ND + c] = f2bf(v);
        }
    }
}

// ---------------- fused layer 2 + linear head (32-row tile) ----------------
__launch_bounds__(256, 8)
__global__ void k_layer2_fused_head(const unsigned short* __restrict__ feat,
                                    const unsigned short* __restrict__ Wt,
                                    const float* __restrict__ bias,
                                    const float* __restrict__ Wlin,
                                    const float* __restrict__ blin,
                                    const int* __restrict__ cnt,
                                    const int* __restrict__ ebuk,
                                    float* __restrict__ out, int n) {
    __shared__ __align__(16) unsigned short Agg[TM * AGS];
    __shared__ __align__(16) unsigned short Sf[TM * AGS];
    __shared__ float part[TM][4];
    const int t = threadIdx.x;
    const int m0 = blockIdx.x * TM;

    gatherTM(feat, cnt, ebuk, n, m0, t, Agg);
    stageSelf(feat, n, m0, t, Sf);
    __syncthreads();

    const int wave = t >> 6, lane = t & 63;
    const int l31 = lane & 31, lhalf = lane >> 5;
    const int wn = wave * 32;
    const unsigned short* Bw = Wt + wave * 8192;

    floatx16 acc = (floatx16)0.0f;

#pragma unroll
    for (int kc = 0; kc < 8; ++kc) {
        const unsigned short* Ab = (kc < 4)
            ? &Agg[l31 * AGS + kc * 32]
            : &Sf[l31 * AGS + (kc - 4) * 32];
        bf16x8 af[2], bfr[2];
#pragma unroll
        for (int ks = 0; ks < 2; ++ks) {
            af[ks]  = *(const bf16x8*)(Ab + ks * 16 + lhalf * 8);
            bfr[ks] = *(const bf16x8*)(Bw + kc * 1024 + ks * 512 + lane * 8);
        }
        acc = __builtin_amdgcn_mfma_f32_32x32x16_bf16(af[0], bfr[0], acc, 0, 0, 0);
        acc = __builtin_amdgcn_mfma_f32_32x32x16_bf16(af[1], bfr[1], acc, 0, 0, 0);
    }

    // fused epilogue: p[reg] = sum_c relu(h2[row][c]) * Wlin[c] over this wave's 32 cols,
    // reduced across the 32 lanes; 4 waves' partials combined via LDS.
    const int c = wn + l31;
    const float bv = bias[c];
    const float wv = Wlin[c];
    float p[16];
#pragma unroll
    for (int reg = 0; reg < 16; ++reg)
        p[reg] = fmaxf(acc[reg] + bv, 0.f) * wv;
#pragma unroll
    for (int reg = 0; reg < 16; ++reg) {
        float v = p[reg];
        v += __shfl_xor(v, 1);
        v += __shfl_xor(v, 2);
        v += __shfl_xor(v, 4);
        v += __shfl_xor(v, 8);
        v += __shfl_xor(v, 16);
        if (l31 == 0) {
            int rl = lhalf * 4 + (reg & 3) + 8 * (reg >> 2);
            part[rl][wave] = v;
        }
    }
    __syncthreads();
    if (t < TM) {
        int row = m0 + t;
        if (row < n)
            out[row] = part[t][0] + part[t][1] + part[t][2] + part[t][3] + blin[0];
    }
}

extern "C" void kernel_launch(void* const* d_in, const int* in_sizes, int n_in,
                              void* d_out, int out_size, void* d_ws, size_t ws_size,
                              hipStream_t stream) {
    const float* x    = (const float*)d_in[0];
    const int*   edge = (const int*)d_in[1];    // [2, E]
    const float* W1l  = (const float*)d_in[2];
    const float* b1   = (const float*)d_in[3];
    const float* W1r  = (const float*)d_in[4];
    const float* W2l  = (const float*)d_in[5];
    const float* b2   = (const float*)d_in[6];
    const float* W2r  = (const float*)d_in[7];
    const float* Wlin = (const float*)d_in[8];
    const float* blin = (const float*)d_in[9];
    float* out = (float*)d_out;

    int n = out_size;               // 100000 nodes
    int E = in_sizes[1] / 2;        // 640000 edges
    (void)n_in; (void)ws_size;

    char* ws = (char*)d_ws;
    size_t off = 0;
    auto take = [&](size_t bytes) -> char* {
        char* p = ws + off;
        off += (bytes + 255) & ~(size_t)255;
        return p;
    };
    int* cnt    = (int*)take((size_t)n * 4);
    int* ebuk   = (int*)take((size_t)n * CAP * 4);
    unsigned short* xbf  = (unsigned short*)take((size_t)n * ND * 2);
    unsigned short* h1bf = (unsigned short*)take((size_t)n * ND * 2);
    unsigned short* Wt1  = (unsigned short*)take((size_t)ND * KTOT * 2);
    unsigned short* Wt2  = (unsigned short*)take((size_t)ND * KTOT * 2);

    hipMemsetAsync(cnt, 0, (size_t)n * 4, stream);

    const int* esrc_in = edge;       // row 0: src
    const int* edst_in = edge + E;   // row 1: dst

    int nElems = n * ND;                         // 12.8M
    int prepBlocks = (nElems / 8 + 255) / 256;   // 6250; 128 edges/block covers E=640k

    k_prep_all<<<prepBlocks, 256, 0, stream>>>(
        x, xbf, nElems, W1l, W1r, Wt1, W2l, W2r, Wt2,
        esrc_in, edst_in, cnt, ebuk, E);

    int gemmBlocks = (n + TM - 1) / TM;          // 3125

    // layer 1 (gather + GEMM fused)
    k_layer1_fused<<<gemmBlocks, 256, 0, stream>>>(xbf, Wt1, b1, cnt, ebuk, h1bf, n);
    // layer 2 + head (gather + GEMM + head fused; h2 never materialized)
    k_layer2_fused_head<<<gemmBlocks, 256, 0, stream>>>(h1bf, Wt2, b2, Wlin, blin, cnt, ebuk, out, n);
}

// Round 5
// 214.585 us; speedup vs baseline: 1.1664x; 1.0037x over previous
//
#include <hip/hip_runtime.h>
#include <hip/hip_bf16.h>

// GraphSAGE 2-layer + linear head, N=100000, d=h=128, E=640000.
// R14: attack gather latency (45us fused kernels show no saturated pipe ->
//      dependent-load latency, MLP too low). Chunk-8 gather with zero-row
//      padding: index list prefetched as 2x int4, pad slots select a zeroed
//      row N via cndmask (L1-resident, free) -> 8 independent row loads in
//      flight, no per-chunk serial index load, no masking VALU.
//      launch_bounds (256,6) to avoid spill at ~60 live VGPRs (measured
//      occupancy ~60% never hit the 75% cap). R13's packed-Wt GEMM unchanged.

#define ND 128          // feature dim
#define KTOT 256        // concat K ([agg | self])
#define CAP 32          // neighbor bucket capacity (max deg ~23 @ Poisson 6.4)
#define TM 32           // rows per block
#define AGS 136         // LDS row stride in shorts (272B rows, 16B-aligned)

typedef __bf16 bf16x8 __attribute__((ext_vector_type(8)));
typedef float floatx16 __attribute__((ext_vector_type(16)));

__device__ inline unsigned short f2bf(float f) {
    union { float f; unsigned u; } v; v.f = f;
    unsigned r = v.u + 0x7fffu + ((v.u >> 16) & 1u);   // RTNE
    return (unsigned short)(r >> 16);
}
__device__ inline float bf_lo(unsigned u) { return __uint_as_float(u << 16); }
__device__ inline float bf_hi(unsigned u) { return __uint_as_float(u & 0xffff0000u); }

// ---------------- prep: interleaved jobs — 128 edges/block + convert + weights ----------------
// Wt packed layout (per layer, 64KB): for output-slab n32 (0..3), kc (0..7),
// ks (0..1): a 1KB chunk of 64 lanes x 16B, lane = (lhalf<<5)|l31 holding
// W[kc*32+ks*16+lhalf*8 + 0..7][n32*32+l31]. One coalesced wave load per frag.
// Also zeroes row N of xbf and h1bf (the gather's zero-row pad target).
__global__ void k_prep_all(const float* __restrict__ x, unsigned short* __restrict__ xbf,
                           unsigned short* __restrict__ h1bf, int n,
                           int nElems,
                           const float* __restrict__ W1l, const float* __restrict__ W1r,
                           unsigned short* __restrict__ Wt1,
                           const float* __restrict__ W2l, const float* __restrict__ W2r,
                           unsigned short* __restrict__ Wt2,
                           const int* __restrict__ esrc_in, const int* __restrict__ edst_in,
                           int* __restrict__ cnt, int* __restrict__ ebuk, int E) {
    const int t = threadIdx.x;
    const int tid = blockIdx.x * 256 + t;

    // --- edge job: threads 0..127 take one edge each (coalesced 512B) ---
    const int e = blockIdx.x * 128 + t;
    const bool doE = (t < 128) && (e < E);
    int d0 = 0, s0 = 0;
    if (doE) {
        d0 = edst_in[e];
        s0 = esrc_in[e];
    }

    // --- x loads (independent; overlap the atomic below) ---
    const int i = tid * 8;
    float4 xa, xc;
    const bool doX = (i < nElems);
    if (doX) {
        xa = *(const float4*)(x + i);
        xc = *(const float4*)(x + i + 4);
    }

    // --- atomic slot claim ---
    int p0 = -1;
    if (doE) p0 = atomicAdd(&cnt[d0], 1);

    // --- convert + store (VALU/BW work hides the atomic round trip) ---
    if (doX) {
        uint4 r;
        r.x = (unsigned)f2bf(xa.x) | ((unsigned)f2bf(xa.y) << 16);
        r.y = (unsigned)f2bf(xa.z) | ((unsigned)f2bf(xa.w) << 16);
        r.z = (unsigned)f2bf(xc.x) | ((unsigned)f2bf(xc.y) << 16);
        r.w = (unsigned)f2bf(xc.z) | ((unsigned)f2bf(xc.w) << 16);
        *(uint4*)(xbf + i) = r;
    }

    // --- zero-row pad target: row n of xbf and h1bf (16 int4 each) ---
    if (tid < 32) {
        int4 z = {0, 0, 0, 0};
        unsigned short* zp = (tid < 16) ? xbf : h1bf;
        ((int4*)(zp + (size_t)n * ND))[tid & 15] = z;
    }

    // --- weight transpose+convert into packed fragment order (tiny) ---
    if (tid < 2 * KTOT * ND) {
        const int half = tid >> 15;            // 0 -> layer1, 1 -> layer2
        const int idx = tid & 32767;
        const int nn = idx >> 8;               // output col 0..127
        const int kk = idx & 255;              // concat K 0..255
        const float* Wl = half ? W2l : W1l;
        const float* Wr = half ? W2r : W1r;
        unsigned short* Wt = half ? Wt2 : Wt1;
        float v = (kk < 128) ? Wl[(size_t)kk * ND + nn] : Wr[(size_t)(kk - 128) * ND + nn];
        const int n32 = nn >> 5, r = nn & 31;
        const int kc = kk >> 5, ks = (kk >> 4) & 1, lh = (kk >> 3) & 1, k8 = kk & 7;
        Wt[n32 * 8192 + kc * 1024 + ks * 512 + (lh * 32 + r) * 8 + k8] = f2bf(v);
    }

    // --- dependent scatter store ---
    if (p0 >= 0 && p0 < CAP) ebuk[d0 * CAP + p0] = s0;
}

// ---------------- fused gather: TM rows -> Agg LDS (16 lanes/node, chunk-8, zero-row pad) ----------------
__device__ __forceinline__ void gatherTM(const unsigned short* __restrict__ feat,
                                         const int* __restrict__ cnt,
                                         const int* __restrict__ ebuk,
                                         int n, int m0, int t,
                                         unsigned short* Agg) {
    const int l = t & 15;
    const int g = t >> 4;
#pragma unroll
    for (int p = 0; p < TM / 16; ++p) {
        const int nl = p * 16 + g;             // node_local 0..TM-1
        const int node = m0 + nl;
        int d = 0;
        if (node < n) d = cnt[node];
        const int dd = min(d, CAP);
        const int4* lst4 = (const int4*)(ebuk + (size_t)node * CAP);
        // prefetch first 8 indices (2 loads, off the row-load critical path);
        // entries beyond dd are stale garbage but are replaced by the zero-row
        // index n below before any dereference.
        const int4 L0 = lst4[0];
        const int4 L1 = lst4[1];
        int s[8];
        s[0] = (0 < dd) ? L0.x : n;
        s[1] = (1 < dd) ? L0.y : n;
        s[2] = (2 < dd) ? L0.z : n;
        s[3] = (3 < dd) ? L0.w : n;
        s[4] = (4 < dd) ? L1.x : n;
        s[5] = (5 < dd) ? L1.y : n;
        s[6] = (6 < dd) ? L1.z : n;
        s[7] = (7 < dd) ? L1.w : n;
        uint4 v[8];
#pragma unroll
        for (int k = 0; k < 8; ++k)
            v[k] = ((const uint4*)(feat + (size_t)s[k] * ND))[l];
        float a[8] = {0.f, 0.f, 0.f, 0.f, 0.f, 0.f, 0.f, 0.f};
#pragma unroll
        for (int k = 0; k < 8; ++k) {
            a[0] += bf_lo(v[k].x); a[1] += bf_hi(v[k].x);
            a[2] += bf_lo(v[k].y); a[3] += bf_hi(v[k].y);
            a[4] += bf_lo(v[k].z); a[5] += bf_hi(v[k].z);
            a[6] += bf_lo(v[k].w); a[7] += bf_hi(v[k].w);
        }
        if (dd > 8) {                           // rare tail (deg>8, ~3% of nodes)
            for (int j = 8; j < dd; j += 8) {
                const int4 M0 = lst4[j >> 2];
                const int4 M1 = lst4[(j >> 2) + 1];
                int q[8];
                q[0] = (j + 0 < dd) ? M0.x : n;
                q[1] = (j + 1 < dd) ? M0.y : n;
                q[2] = (j + 2 < dd) ? M0.z : n;
                q[3] = (j + 3 < dd) ? M0.w : n;
                q[4] = (j + 4 < dd) ? M1.x : n;
                q[5] = (j + 5 < dd) ? M1.y : n;
                q[6] = (j + 6 < dd) ? M1.z : n;
                q[7] = (j + 7 < dd) ? M1.w : n;
                uint4 w[8];
#pragma unroll
                for (int k = 0; k < 8; ++k)
                    w[k] = ((const uint4*)(feat + (size_t)q[k] * ND))[l];
#pragma unroll
                for (int k = 0; k < 8; ++k) {
                    a[0] += bf_lo(w[k].x); a[1] += bf_hi(w[k].x);
                    a[2] += bf_lo(w[k].y); a[3] += bf_hi(w[k].y);
                    a[4] += bf_lo(w[k].z); a[5] += bf_hi(w[k].z);
                    a[6] += bf_lo(w[k].w); a[7] += bf_hi(w[k].w);
                }
            }
        }
        float inv = 1.0f / (float)max(d, 1);
        uint4 r;
        r.x = (unsigned)f2bf(a[0] * inv) | ((unsigned)f2bf(a[1] * inv) << 16);
        r.y = (unsigned)f2bf(a[2] * inv) | ((unsigned)f2bf(a[3] * inv) << 16);
        r.z = (unsigned)f2bf(a[4] * inv) | ((unsigned)f2bf(a[5] * inv) << 16);
        r.w = (unsigned)f2bf(a[6] * inv) | ((unsigned)f2bf(a[7] * inv) << 16);
        *(uint4*)&Agg[nl * AGS + l * 8] = r;
    }
}

// ---------------- stage self rows m0..m0+TM-1 into LDS (coalesced) ----------------
__device__ __forceinline__ void stageSelf(const unsigned short* __restrict__ feat,
                                          int n, int m0, int t,
                                          unsigned short* Sf) {
#pragma unroll
    for (int q = 0; q < (TM * ND / 8) / 256; ++q) {     // 512 int4 chunks / 256 threads
        const int idx = t + q * 256;                    // 0..511
        const int row = idx >> 4;                       // 16 int4 per 128-short row
        const int c16 = idx & 15;
        int4 w = {0, 0, 0, 0};
        const int gr = m0 + row;
        if (gr < n) w = *(const int4*)(feat + (size_t)gr * ND + c16 * 8);
        *(int4*)&Sf[row * AGS + c16 * 8] = w;
    }
}

// ---------------- fused layer 1: gather + MFMA GEMM (32-row tile, 4 N-waves) ----------------
__launch_bounds__(256, 6)
__global__ void k_layer1_fused(const unsigned short* __restrict__ feat,
                               const unsigned short* __restrict__ Wt,
                               const float* __restrict__ bias,
                               const int* __restrict__ cnt,
                               const int* __restrict__ ebuk,
                               unsigned short* __restrict__ out, int n) {
    __shared__ __align__(16) unsigned short Agg[TM * AGS];
    __shared__ __align__(16) unsigned short Sf[TM * AGS];
    const int t = threadIdx.x;
    const int m0 = blockIdx.x * TM;

    gatherTM(feat, cnt, ebuk, n, m0, t, Agg);
    stageSelf(feat, n, m0, t, Sf);
    __syncthreads();

    const int wave = t >> 6, lane = t & 63;
    const int l31 = lane & 31, lhalf = lane >> 5;
    const int wn = wave * 32;                  // 4 waves split N=128 into 32-col slabs
    const unsigned short* Bw = Wt + wave * 8192;

    floatx16 acc = (floatx16)0.0f;

#pragma unroll
    for (int kc = 0; kc < 8; ++kc) {
        const unsigned short* Ab = (kc < 4)
            ? &Agg[l31 * AGS + kc * 32]
            : &Sf[l31 * AGS + (kc - 4) * 32];
        bf16x8 af[2], bfr[2];
#pragma unroll
        for (int ks = 0; ks < 2; ++ks) {
            af[ks]  = *(const bf16x8*)(Ab + ks * 16 + lhalf * 8);
            bfr[ks] = *(const bf16x8*)(Bw + kc * 1024 + ks * 512 + lane * 8);
        }
        acc = __builtin_amdgcn_mfma_f32_32x32x16_bf16(af[0], bfr[0], acc, 0, 0, 0);
        acc = __builtin_amdgcn_mfma_f32_32x32x16_bf16(af[1], bfr[1], acc, 0, 0, 0);
    }

    // epilogue: relu + bf16 store. C/D: col=lane&31, row=(reg&3)+8*(reg>>2)+4*(lane>>5)
    const int c = wn + l31;
    const float bv = bias[c];
#pragma unroll
    for (int reg = 0; reg < 16; ++reg) {
        const int row = m0 + lhalf * 4 + (reg & 3) + 8 * (reg >> 2);
        if (row < n) {
            float v = fmaxf(acc[reg] + bv, 0.f);
            out[(size_t)row * ND + c] = f2bf(v);
        }
    }
}

// ---------------- fused layer 2 + linear head (32-row tile) ----------------
__launch_bounds__(256, 6)
__global__ void k_layer2_fused_head(const unsigned short* __restrict__ feat,
                                    const unsigned short* __restrict__ Wt,
                                    const float* __restrict__ bias,
                                    const float* __restrict__ Wlin,
                                    const float* __restrict__ blin,
                                    const int* __restrict__ cnt,
                                    const int* __restrict__ ebuk,
                                    float* __restrict__ out, int n) {
    __shared__ __align__(16) unsigned short Agg[TM * AGS];
    __shared__ __align__(16) unsigned short Sf[TM * AGS];
    __shared__ float part[TM][4];
    const int t = threadIdx.x;
    const int m0 = blockIdx.x * TM;

    gatherTM(feat, cnt, ebuk, n, m0, t, Agg);
    stageSelf(feat, n, m0, t, Sf);
    __syncthreads();

    const int wave = t >> 6, lane = t & 63;
    const int l31 = lane & 31, lhalf = lane >> 5;
    const int wn = wave * 32;
    const unsigned short* Bw = Wt + wave * 8192;

    floatx16 acc = (floatx16)0.0f;

#pragma unroll
    for (int kc = 0; kc < 8; ++kc) {
        const unsigned short* Ab = (kc < 4)
            ? &Agg[l31 * AGS + kc * 32]
            : &Sf[l31 * AGS + (kc - 4) * 32];
        bf16x8 af[2], bfr[2];
#pragma unroll
        for (int ks = 0; ks < 2; ++ks) {
            af[ks]  = *(const bf16x8*)(Ab + ks * 16 + lhalf * 8);
            bfr[ks] = *(const bf16x8*)(Bw + kc * 1024 + ks * 512 + lane * 8);
        }
        acc = __builtin_amdgcn_mfma_f32_32x32x16_bf16(af[0], bfr[0], acc, 0, 0, 0);
        acc = __builtin_amdgcn_mfma_f32_32x32x16_bf16(af[1], bfr[1], acc, 0, 0, 0);
    }

    // fused epilogue: p[reg] = sum_c relu(h2[row][c]) * Wlin[c] over this wave's 32 cols,
    // reduced across the 32 lanes; 4 waves' partials combined via LDS.
    const int c = wn + l31;
    const float bv = bias[c];
    const float wv = Wlin[c];
    float p[16];
#pragma unroll
    for (int reg = 0; reg < 16; ++reg)
        p[reg] = fmaxf(acc[reg] + bv, 0.f) * wv;
#pragma unroll
    for (int reg = 0; reg < 16; ++reg) {
        float v = p[reg];
        v += __shfl_xor(v, 1);
        v += __shfl_xor(v, 2);
        v += __shfl_xor(v, 4);
        v += __shfl_xor(v, 8);
        v += __shfl_xor(v, 16);
        if (l31 == 0) {
            int rl = lhalf * 4 + (reg & 3) + 8 * (reg >> 2);
            part[rl][wave] = v;
        }
    }
    __syncthreads();
    if (t < TM) {
        int row = m0 + t;
        if (row < n)
            out[row] = part[t][0] + part[t][1] + part[t][2] + part[t][3] + blin[0];
    }
}

extern "C" void kernel_launch(void* const* d_in, const int* in_sizes, int n_in,
                              void* d_out, int out_size, void* d_ws, size_t ws_size,
                              hipStream_t stream) {
    const float* x    = (const float*)d_in[0];
    const int*   edge = (const int*)d_in[1];    // [2, E]
    const float* W1l  = (const float*)d_in[2];
    const float* b1   = (const float*)d_in[3];
    const float* W1r  = (const float*)d_in[4];
    const float* W2l  = (const float*)d_in[5];
    const float* b2   = (const float*)d_in[6];
    const float* W2r  = (const float*)d_in[7];
    const float* Wlin = (const float*)d_in[8];
    const float* blin = (const float*)d_in[9];
    float* out = (float*)d_out;

    int n = out_size;               // 100000 nodes
    int E = in_sizes[1] / 2;        // 640000 edges
    (void)n_in; (void)ws_size;

    char* ws = (char*)d_ws;
    size_t off = 0;
    auto take = [&](size_t bytes) -> char* {
        char* p = ws + off;
        off += (bytes + 255) & ~(size_t)255;
        return p;
    };
    int* cnt    = (int*)take((size_t)n * 4);
    int* ebuk   = (int*)take((size_t)n * CAP * 4);
    unsigned short* xbf  = (unsigned short*)take((size_t)(n + 1) * ND * 2);  // +1 zero row
    unsigned short* h1bf = (unsigned short*)take((size_t)(n + 1) * ND * 2);  // +1 zero row
    unsigned short* Wt1  = (unsigned short*)take((size_t)ND * KTOT * 2);
    unsigned short* Wt2  = (unsigned short*)take((size_t)ND * KTOT * 2);

    hipMemsetAsync(cnt, 0, (size_t)n * 4, stream);

    const int* esrc_in = edge;       // row 0: src
    const int* edst_in = edge + E;   // row 1: dst

    int nElems = n * ND;                         // 12.8M
    int prepBlocks = (nElems / 8 + 255) / 256;   // 6250; 128 edges/block covers E=640k

    k_prep_all<<<prepBlocks, 256, 0, stream>>>(
        x, xbf, h1bf, n, nElems, W1l, W1r, Wt1, W2l, W2r, Wt2,
        esrc_in, edst_in, cnt, ebuk, E);

    int gemmBlocks = (n + TM - 1) / TM;          // 3125

    // layer 1 (gather + GEMM fused)
    k_layer1_fused<<<gemmBlocks, 256, 0, stream>>>(xbf, Wt1, b1, cnt, ebuk, h1bf, n);
    // layer 2 + head (gather + GEMM + head fused; h2 never materialized)
    k_layer2_fused_head<<<gemmBlocks, 256, 0, stream>>>(h1bf, Wt2, b2, Wlin, blin, cnt, ebuk, out, n);
}